// Round 7
// baseline (13443.008 us; speedup 1.0000x reference)
//
#include <hip/hip_runtime.h>
#include <hip/hip_bf16.h>

#define Bn 8
#define Tn 2048
#define Cn 1024

typedef __attribute__((ext_vector_type(8))) short short8;
typedef __attribute__((ext_vector_type(4))) float f32x4;

__device__ __forceinline__ unsigned short f2bf(float x) {
    union { float f; unsigned u; } v; v.f = x;
    return (unsigned short)((v.u + 0x7FFFu + ((v.u >> 16) & 1u)) >> 16);
}

// ---------------------------------------------------------------------------
// K0: transpose W [c][d] f32 -> WT [d][c] bf16  (1024x1024), 256 blocks/weight
// ---------------------------------------------------------------------------
__global__ __launch_bounds__(256) void transpose_cvt(const float* __restrict__ W,
                                                     unsigned short* __restrict__ WT) {
    __shared__ float tile[64][65];
    const int bx = blockIdx.x;          // 0..255
    const int tr = (bx >> 4) << 6;      // c-block
    const int tc = (bx & 15) << 6;      // d-block
    const int tid = threadIdx.x;
    const int r  = tid >> 2;            // 0..63
    const int c4 = (tid & 3) << 4;      // 0,16,32,48
#pragma unroll
    for (int i = 0; i < 4; ++i) {
        float4 v = *(const float4*)(W + (long)(tr + r) * Cn + tc + c4 + i * 4);
        tile[r][c4 + i * 4 + 0] = v.x;
        tile[r][c4 + i * 4 + 1] = v.y;
        tile[r][c4 + i * 4 + 2] = v.z;
        tile[r][c4 + i * 4 + 3] = v.w;
    }
    __syncthreads();
    // WT[tc+r][tr+c4+i] = W[tr+c4+i][tc+r] = tile[c4+i][r]
    short8 p0, p1;
#pragma unroll
    for (int i = 0; i < 8; ++i)  p0[i] = (short)f2bf(tile[c4 + i][r]);
#pragma unroll
    for (int i = 0; i < 8; ++i)  p1[i] = (short)f2bf(tile[c4 + 8 + i][r]);
    unsigned short* dst = WT + (long)(tc + r) * Cn + tr + c4;
    *(short8*)(dst)     = p0;
    *(short8*)(dst + 8) = p1;
}

// ---------------------------------------------------------------------------
// K1: fused A = (sum(relu(XWq)*relu(XWk))) * (XWv)
// 256 wgs x 256 thr; each wg owns 64 rows. LDS: X 128K + 2x16K B tiles = 160K
// ---------------------------------------------------------------------------
__global__ __launch_bounds__(256, 1) void qkv_fused(const float* __restrict__ X,
                                                    const unsigned short* __restrict__ WqT,
                                                    const unsigned short* __restrict__ WkT,
                                                    const unsigned short* __restrict__ WvT,
                                                    float* __restrict__ Aout) {
    extern __shared__ char smem[];
    char* xs = smem;                 // [64][1024] bf16, swizzled
    char* b0 = smem + 131072;        // [128][64] bf16, swizzled
    char* b1 = smem + 147456;        // [128][64] bf16, swizzled
    const int tid = threadIdx.x;
    const long row0 = (long)blockIdx.x * 64;

    // ---- stage X (64 x 1024) f32 -> bf16 LDS, XOR-swizzled 16B slots ----
#pragma unroll 4
    for (int it = 0; it < 32; ++it) {
        int chunk = it * 256 + tid;      // 8192 chunks of 8 elems
        int r  = chunk >> 7;             // 0..63
        int cc = chunk & 127;            // 16B slot in row
        const float* src = X + (row0 + r) * Cn + cc * 8;
        float4 v0 = *(const float4*)src;
        float4 v1 = *(const float4*)(src + 4);
        short8 p;
        p[0] = (short)f2bf(v0.x); p[1] = (short)f2bf(v0.y);
        p[2] = (short)f2bf(v0.z); p[3] = (short)f2bf(v0.w);
        p[4] = (short)f2bf(v1.x); p[5] = (short)f2bf(v1.y);
        p[6] = (short)f2bf(v1.z); p[7] = (short)f2bf(v1.w);
        *(short8*)(xs + r * 2048 + ((cc * 16) ^ ((r & 7) << 4))) = p;
    }

    const int lane = tid & 63;
    const int wv   = tid >> 6;     // wave 0..3
    const int wm   = wv & 1;       // m-half
    const int wn   = wv >> 1;      // n-half
    const int m0   = wm * 32;
    const int l15  = lane & 15;
    const int lk   = lane >> 4;    // 0..3

    float s_part[2][4] = {};

    // ---------------- QK phase: accumulate s ----------------
    for (int nb = 0; nb < 8; ++nb) {
        const int n0 = nb * 128;
        f32x4 qa[2][4] = {};
        f32x4 ka[2][4] = {};
        for (int k0 = 0; k0 < 16; ++k0) {
            const int kk = k0 * 64;
            __syncthreads();
            // stage Wq->b0, Wk->b1 tiles [128n x 64k]
#pragma unroll
            for (int i = 0; i < 4; ++i) {
                int ch = i * 256 + tid;
                int n  = ch >> 3;
                int s  = ch & 7;
                int loff = n * 128 + ((s * 16) ^ ((n & 7) << 4));
                long goff = (long)(n0 + n) * Cn + kk + s * 8;
                *(short8*)(b0 + loff) = *(const short8*)(WqT + goff);
                *(short8*)(b1 + loff) = *(const short8*)(WkT + goff);
            }
            __syncthreads();
#pragma unroll
            for (int ki = 0; ki < 2; ++ki) {
                const int kb  = (kk + ki * 32 + lk * 8) * 2;   // byte-in-row of X
                const int r0  = m0 + l15, r1 = m0 + 16 + l15;
                short8 a0 = *(const short8*)(xs + r0 * 2048 + (kb ^ ((r0 & 7) << 4)));
                short8 a1 = *(const short8*)(xs + r1 * 2048 + (kb ^ ((r1 & 7) << 4)));
                const int bkb = (ki * 32 + lk * 8) * 2;        // byte-in-row of B tile
#pragma unroll
                for (int nf = 0; nf < 4; ++nf) {
                    int n = wn * 64 + nf * 16 + l15;
                    int boff = n * 128 + (bkb ^ ((n & 7) << 4));
                    short8 bq = *(const short8*)(b0 + boff);
                    qa[0][nf] = __builtin_amdgcn_mfma_f32_16x16x32_bf16(a0, bq, qa[0][nf], 0, 0, 0);
                    qa[1][nf] = __builtin_amdgcn_mfma_f32_16x16x32_bf16(a1, bq, qa[1][nf], 0, 0, 0);
                    short8 bk = *(const short8*)(b1 + boff);
                    ka[0][nf] = __builtin_amdgcn_mfma_f32_16x16x32_bf16(a0, bk, ka[0][nf], 0, 0, 0);
                    ka[1][nf] = __builtin_amdgcn_mfma_f32_16x16x32_bf16(a1, bk, ka[1][nf], 0, 0, 0);
                }
            }
        }
#pragma unroll
        for (int mf = 0; mf < 2; ++mf)
#pragma unroll
            for (int nf = 0; nf < 4; ++nf)
#pragma unroll
                for (int r = 0; r < 4; ++r) {
                    float q = fmaxf(qa[mf][nf][r], 0.f);
                    float k = fmaxf(ka[mf][nf][r], 0.f);
                    s_part[mf][r] += q * k;
                }
    }
    // reduce s across the 16 column-lanes (stays inside l>>4 groups)
#pragma unroll
    for (int mf = 0; mf < 2; ++mf)
#pragma unroll
        for (int r = 0; r < 4; ++r) {
            float v = s_part[mf][r];
            v += __shfl_xor(v, 1);
            v += __shfl_xor(v, 2);
            v += __shfl_xor(v, 4);
            v += __shfl_xor(v, 8);
            s_part[mf][r] = v;
        }

    // ---- cross-wave reduction over the two wn column-halves (b1 is free) ----
    {
        float* s_red = (float*)b1;   // [2][64]
        if (l15 == 0) {
#pragma unroll
            for (int mf = 0; mf < 2; ++mf)
#pragma unroll
                for (int r = 0; r < 4; ++r)
                    s_red[wn * 64 + m0 + mf * 16 + lk * 4 + r] = s_part[mf][r];
        }
        __syncthreads();
#pragma unroll
        for (int mf = 0; mf < 2; ++mf)
#pragma unroll
            for (int r = 0; r < 4; ++r) {
                int row = m0 + mf * 16 + lk * 4 + r;
                s_part[mf][r] = s_red[row] + s_red[64 + row];
            }
        __syncthreads();
    }

    // ---------------- V phase: A = s * (X Wv) ----------------
    for (int nb = 0; nb < 8; ++nb) {
        const int n0 = nb * 128;
        f32x4 va[2][4] = {};
        for (int k0 = 0; k0 < 16; ++k0) {
            const int kk = k0 * 64;
            __syncthreads();
#pragma unroll
            for (int i = 0; i < 4; ++i) {
                int ch = i * 256 + tid;
                int n  = ch >> 3;
                int s  = ch & 7;
                *(short8*)(b0 + n * 128 + ((s * 16) ^ ((n & 7) << 4))) =
                    *(const short8*)(WvT + (long)(n0 + n) * Cn + kk + s * 8);
            }
            __syncthreads();
#pragma unroll
            for (int ki = 0; ki < 2; ++ki) {
                const int kb  = (kk + ki * 32 + lk * 8) * 2;
                const int r0  = m0 + l15, r1 = m0 + 16 + l15;
                short8 a0 = *(const short8*)(xs + r0 * 2048 + (kb ^ ((r0 & 7) << 4)));
                short8 a1 = *(const short8*)(xs + r1 * 2048 + (kb ^ ((r1 & 7) << 4)));
                const int bkb = (ki * 32 + lk * 8) * 2;
#pragma unroll
                for (int nf = 0; nf < 4; ++nf) {
                    int n = wn * 64 + nf * 16 + l15;
                    short8 bv = *(const short8*)(b0 + n * 128 + (bkb ^ ((n & 7) << 4)));
                    va[0][nf] = __builtin_amdgcn_mfma_f32_16x16x32_bf16(a0, bv, va[0][nf], 0, 0, 0);
                    va[1][nf] = __builtin_amdgcn_mfma_f32_16x16x32_bf16(a1, bv, va[1][nf], 0, 0, 0);
                }
            }
        }
#pragma unroll
        for (int mf = 0; mf < 2; ++mf)
#pragma unroll
            for (int nf = 0; nf < 4; ++nf)
#pragma unroll
                for (int r = 0; r < 4; ++r) {
                    long row = row0 + m0 + mf * 16 + lk * 4 + r;
                    int  col = n0 + wn * 64 + nf * 16 + l15;
                    Aout[row * Cn + col] = s_part[mf][r] * va[mf][nf][r];
                }
    }
}

// ---------------------------------------------------------------------------
// K2: serial recurrence h_t = tanh(W_hh h_{t-1} + b_hh + A_{t-1})
// 256 wgs: wg = (batch b = blockIdx&7, slice = blockIdx>>3) owns 32 columns.
// Fence-free tag-in-data protocol (unchanged from R4). New structure:
//  - thread (g=tid>>5, l=tid&31) polls exactly the 4 h-words its half-wave
//    group consumes -> h exchange via broadcast shfl, NO LDS stage, NO barrier
//  - pipelined poll: two outstanding load sets halve the detect period
//  - shfl_xor(32) folds half-wave partials; single barrier/step; tid<32 sums
//    4 wave partials, tanh, publishes cbuf BEFORE the out store
// ---------------------------------------------------------------------------
#define LDW(i) __hip_atomic_load(src + (i), __ATOMIC_RELAXED, __HIP_MEMORY_SCOPE_AGENT)

__global__ __launch_bounds__(256, 2)
void recurrence(const float* __restrict__ A,
                const float* __restrict__ Whh,
                const float* __restrict__ bhh,
                unsigned long long* __restrict__ cbuf,   // [2][8][1024]
                float* __restrict__ out) {
    const int tid = threadIdx.x;
    const int b   = blockIdx.x & 7;
    const int sl  = blockIdx.x >> 3;     // 0..31
    const int j0  = sl * 32;
    const int g   = tid >> 5;            // 0..7, 128-wide h chunk
    const int l   = tid & 31;            // output column within slice

    __shared__ float sbuf[16000];        // occupancy declaration (62.5 KB)
    float (*part2)[4][32] = (float (*)[4][32])sbuf;   // [2][4][32]

    // W_hh[j0+l][g*128 .. +127] register/AGPR-resident, asm-pinned
    float4 w[32];
    const float4* wp = (const float4*)(Whh + (long)(j0 + l) * Cn + g * 128);
#pragma unroll
    for (int r = 0; r < 32; ++r) w[r] = wp[r];
#pragma unroll
    for (int r = 0; r < 32; ++r) {
        asm volatile("" : "+v"(w[r].x), "+v"(w[r].y), "+v"(w[r].z), "+v"(w[r].w));
    }

    const float bh = (tid < 32) ? bhh[j0 + tid] : 0.f;
    const int   sb = tid & 32;           // shfl base of my half-wave

    for (int t = 1; t <= Tn; ++t) {
        // A prefetch for the finisher (overlaps the poll)
        float a_val = 0.f;
        if (tid < 32) a_val = A[((long)b * Tn + (t - 1)) * Cn + j0 + tid];

        // ---- pipelined poll of my group's 4 h words ----
        unsigned long long* src =
            cbuf + ((size_t)((t - 1) & 1) * Bn + b) * Cn + g * 128 + l * 4;
        const unsigned expect = (unsigned)(t - 1);
        float v0 = 0.f, v1 = 0.f, v2 = 0.f, v3 = 0.f;
        unsigned pend = 0xF;
        unsigned long long a0 = LDW(0), a1 = LDW(1), a2 = LDW(2), a3 = LDW(3);
        for (;;) {
            unsigned long long c0 = LDW(0), c1 = LDW(1), c2 = LDW(2), c3 = LDW(3);
            if ((pend & 1u) && (unsigned)(a0 >> 32) == expect) { v0 = __uint_as_float((unsigned)a0); pend &= ~1u; }
            if ((pend & 2u) && (unsigned)(a1 >> 32) == expect) { v1 = __uint_as_float((unsigned)a1); pend &= ~2u; }
            if ((pend & 4u) && (unsigned)(a2 >> 32) == expect) { v2 = __uint_as_float((unsigned)a2); pend &= ~4u; }
            if ((pend & 8u) && (unsigned)(a3 >> 32) == expect) { v3 = __uint_as_float((unsigned)a3); pend &= ~8u; }
            if (!pend) break;
            a0 = LDW(0); a1 = LDW(1); a2 = LDW(2); a3 = LDW(3);
            if ((pend & 1u) && (unsigned)(c0 >> 32) == expect) { v0 = __uint_as_float((unsigned)c0); pend &= ~1u; }
            if ((pend & 2u) && (unsigned)(c1 >> 32) == expect) { v1 = __uint_as_float((unsigned)c1); pend &= ~2u; }
            if ((pend & 4u) && (unsigned)(c2 >> 32) == expect) { v2 = __uint_as_float((unsigned)c2); pend &= ~4u; }
            if ((pend & 8u) && (unsigned)(c3 >> 32) == expect) { v3 = __uint_as_float((unsigned)c3); pend &= ~8u; }
            if (!pend) break;
        }
        // wave reconvergence: all lanes of both half-waves now hold their words

        // ---- dot via half-wave broadcast shfl (no LDS, no barrier) ----
        float ax = 0.f, ay = 0.f, az = 0.f, aw = 0.f;
#pragma unroll
        for (int s = 0; s < 32; ++s) {
            float h0 = __shfl(v0, sb + s, 64);
            float h1 = __shfl(v1, sb + s, 64);
            float h2 = __shfl(v2, sb + s, 64);
            float h3 = __shfl(v3, sb + s, 64);
            ax = fmaf(w[s].x, h0, ax);
            ay = fmaf(w[s].y, h1, ay);
            az = fmaf(w[s].z, h2, az);
            aw = fmaf(w[s].w, h3, aw);
        }
        float pt = (ax + ay) + (az + aw);
        pt += __shfl_xor(pt, 32, 64);    // fold the two half-wave chunks

        if ((tid & 63) < 32) part2[t & 1][tid >> 6][l] = pt;
        __syncthreads();                 // the only barrier per step

        if (tid < 32) {
            float s = (part2[t & 1][0][tid] + part2[t & 1][1][tid]) +
                      (part2[t & 1][2][tid] + part2[t & 1][3][tid]);
            float ht = tanhf(s + a_val + bh);
            // publish FIRST (critical path), then the output store
            unsigned long long pk =
                ((unsigned long long)(unsigned)t << 32) | (unsigned long long)__float_as_uint(ht);
            __hip_atomic_store(cbuf + ((size_t)(t & 1) * Bn + b) * Cn + j0 + tid, pk,
                               __ATOMIC_RELAXED, __HIP_MEMORY_SCOPE_AGENT);
            out[((long)b * Tn + (t - 1)) * Cn + j0 + tid] = ht;
        }
        // no trailing barrier: next step writes part2[(t+1)&1]; part2[t&1] is
        // reused only at t+2, after everyone passed barrier(t+1), which the
        // readers reach only after finishing their reads of part2[t&1].
    }
}

// ---------------------------------------------------------------------------
extern "C" void kernel_launch(void* const* d_in, const int* in_sizes, int n_in,
                              void* d_out, int out_size, void* d_ws, size_t ws_size,
                              hipStream_t stream) {
    const float* X   = (const float*)d_in[0];
    const float* S_n = (const float*)d_in[2];
    const float* W_Q = (const float*)d_in[4];
    const float* W_K = (const float*)d_in[5];
    const float* W_V = (const float*)d_in[6];
    const float* Whh = (const float*)d_in[7];
    const float* bhh = (const float*)d_in[8];
    float* out = (float*)d_out;

    char* ws = (char*)d_ws;
    float*              A     = (float*)ws;                             // 64 MiB
    unsigned short*     WqT   = (unsigned short*)(ws + 67108864);       // 2 MiB
    unsigned short*     WkT   = WqT + 1024 * 1024;
    unsigned short*     WvT   = WkT + 1024 * 1024;
    unsigned long long* cbuf  = (unsigned long long*)(ws + 67108864 + 3 * 2097152); // 128 KiB

    (void)hipFuncSetAttribute((const void*)qkv_fused,
                              hipFuncAttributeMaxDynamicSharedMemorySize, 163840);

    // cbuf zero = (tag 0, value 0.0f) = h_0  -> step 1 is immediately satisfied
    (void)hipMemsetAsync(cbuf, 0, 2 * Bn * Cn * sizeof(unsigned long long), stream);

    transpose_cvt<<<256, 256, 0, stream>>>(W_Q, WqT);
    transpose_cvt<<<256, 256, 0, stream>>>(W_K, WkT);
    transpose_cvt<<<256, 256, 0, stream>>>(W_V, WvT);

    qkv_fused<<<256, 256, 163840, stream>>>(X, WqT, WkT, WvT, A);

    recurrence<<<256, 256, 0, stream>>>(A, Whh, bhh, cbuf, out);

    // S_n passthrough (second output)
    (void)hipMemcpyAsync(out + (long)Bn * Tn * Cn, S_n, Bn * Cn * sizeof(float),
                         hipMemcpyDeviceToDevice, stream);
}

// Round 8
// 4499.937 us; speedup vs baseline: 2.9874x; 2.9874x over previous
//
#include <hip/hip_runtime.h>
#include <hip/hip_bf16.h>

#define Bn 8
#define Tn 2048
#define Cn 1024

typedef __attribute__((ext_vector_type(8))) short short8;
typedef __attribute__((ext_vector_type(4))) float f32x4;

__device__ __forceinline__ unsigned short f2bf(float x) {
    union { float f; unsigned u; } v; v.f = x;
    return (unsigned short)((v.u + 0x7FFFu + ((v.u >> 16) & 1u)) >> 16);
}

// ---------------------------------------------------------------------------
// K0: transpose W [c][d] f32 -> WT [d][c] bf16  (1024x1024), 256 blocks/weight
// ---------------------------------------------------------------------------
__global__ __launch_bounds__(256) void transpose_cvt(const float* __restrict__ W,
                                                     unsigned short* __restrict__ WT) {
    __shared__ float tile[64][65];
    const int bx = blockIdx.x;          // 0..255
    const int tr = (bx >> 4) << 6;      // c-block
    const int tc = (bx & 15) << 6;      // d-block
    const int tid = threadIdx.x;
    const int r  = tid >> 2;            // 0..63
    const int c4 = (tid & 3) << 4;      // 0,16,32,48
#pragma unroll
    for (int i = 0; i < 4; ++i) {
        float4 v = *(const float4*)(W + (long)(tr + r) * Cn + tc + c4 + i * 4);
        tile[r][c4 + i * 4 + 0] = v.x;
        tile[r][c4 + i * 4 + 1] = v.y;
        tile[r][c4 + i * 4 + 2] = v.z;
        tile[r][c4 + i * 4 + 3] = v.w;
    }
    __syncthreads();
    // WT[tc+r][tr+c4+i] = W[tr+c4+i][tc+r] = tile[c4+i][r]
    short8 p0, p1;
#pragma unroll
    for (int i = 0; i < 8; ++i)  p0[i] = (short)f2bf(tile[c4 + i][r]);
#pragma unroll
    for (int i = 0; i < 8; ++i)  p1[i] = (short)f2bf(tile[c4 + 8 + i][r]);
    unsigned short* dst = WT + (long)(tc + r) * Cn + tr + c4;
    *(short8*)(dst)     = p0;
    *(short8*)(dst + 8) = p1;
}

// ---------------------------------------------------------------------------
// K1: fused A = (sum(relu(XWq)*relu(XWk))) * (XWv)
// 256 wgs x 256 thr; each wg owns 64 rows. LDS: X 128K + 2x16K B tiles = 160K
// ---------------------------------------------------------------------------
__global__ __launch_bounds__(256, 1) void qkv_fused(const float* __restrict__ X,
                                                    const unsigned short* __restrict__ WqT,
                                                    const unsigned short* __restrict__ WkT,
                                                    const unsigned short* __restrict__ WvT,
                                                    float* __restrict__ Aout) {
    extern __shared__ char smem[];
    char* xs = smem;                 // [64][1024] bf16, swizzled
    char* b0 = smem + 131072;        // [128][64] bf16, swizzled
    char* b1 = smem + 147456;        // [128][64] bf16, swizzled
    const int tid = threadIdx.x;
    const long row0 = (long)blockIdx.x * 64;

    // ---- stage X (64 x 1024) f32 -> bf16 LDS, XOR-swizzled 16B slots ----
#pragma unroll 4
    for (int it = 0; it < 32; ++it) {
        int chunk = it * 256 + tid;      // 8192 chunks of 8 elems
        int r  = chunk >> 7;             // 0..63
        int cc = chunk & 127;            // 16B slot in row
        const float* src = X + (row0 + r) * Cn + cc * 8;
        float4 v0 = *(const float4*)src;
        float4 v1 = *(const float4*)(src + 4);
        short8 p;
        p[0] = (short)f2bf(v0.x); p[1] = (short)f2bf(v0.y);
        p[2] = (short)f2bf(v0.z); p[3] = (short)f2bf(v0.w);
        p[4] = (short)f2bf(v1.x); p[5] = (short)f2bf(v1.y);
        p[6] = (short)f2bf(v1.z); p[7] = (short)f2bf(v1.w);
        *(short8*)(xs + r * 2048 + ((cc * 16) ^ ((r & 7) << 4))) = p;
    }

    const int lane = tid & 63;
    const int wv   = tid >> 6;     // wave 0..3
    const int wm   = wv & 1;       // m-half
    const int wn   = wv >> 1;      // n-half
    const int m0   = wm * 32;
    const int l15  = lane & 15;
    const int lk   = lane >> 4;    // 0..3

    float s_part[2][4] = {};

    // ---------------- QK phase: accumulate s ----------------
    for (int nb = 0; nb < 8; ++nb) {
        const int n0 = nb * 128;
        f32x4 qa[2][4] = {};
        f32x4 ka[2][4] = {};
        for (int k0 = 0; k0 < 16; ++k0) {
            const int kk = k0 * 64;
            __syncthreads();
            // stage Wq->b0, Wk->b1 tiles [128n x 64k]
#pragma unroll
            for (int i = 0; i < 4; ++i) {
                int ch = i * 256 + tid;
                int n  = ch >> 3;
                int s  = ch & 7;
                int loff = n * 128 + ((s * 16) ^ ((n & 7) << 4));
                long goff = (long)(n0 + n) * Cn + kk + s * 8;
                *(short8*)(b0 + loff) = *(const short8*)(WqT + goff);
                *(short8*)(b1 + loff) = *(const short8*)(WkT + goff);
            }
            __syncthreads();
#pragma unroll
            for (int ki = 0; ki < 2; ++ki) {
                const int kb  = (kk + ki * 32 + lk * 8) * 2;   // byte-in-row of X
                const int r0  = m0 + l15, r1 = m0 + 16 + l15;
                short8 a0 = *(const short8*)(xs + r0 * 2048 + (kb ^ ((r0 & 7) << 4)));
                short8 a1 = *(const short8*)(xs + r1 * 2048 + (kb ^ ((r1 & 7) << 4)));
                const int bkb = (ki * 32 + lk * 8) * 2;        // byte-in-row of B tile
#pragma unroll
                for (int nf = 0; nf < 4; ++nf) {
                    int n = wn * 64 + nf * 16 + l15;
                    int boff = n * 128 + (bkb ^ ((n & 7) << 4));
                    short8 bq = *(const short8*)(b0 + boff);
                    qa[0][nf] = __builtin_amdgcn_mfma_f32_16x16x32_bf16(a0, bq, qa[0][nf], 0, 0, 0);
                    qa[1][nf] = __builtin_amdgcn_mfma_f32_16x16x32_bf16(a1, bq, qa[1][nf], 0, 0, 0);
                    short8 bk = *(const short8*)(b1 + boff);
                    ka[0][nf] = __builtin_amdgcn_mfma_f32_16x16x32_bf16(a0, bk, ka[0][nf], 0, 0, 0);
                    ka[1][nf] = __builtin_amdgcn_mfma_f32_16x16x32_bf16(a1, bk, ka[1][nf], 0, 0, 0);
                }
            }
        }
#pragma unroll
        for (int mf = 0; mf < 2; ++mf)
#pragma unroll
            for (int nf = 0; nf < 4; ++nf)
#pragma unroll
                for (int r = 0; r < 4; ++r) {
                    float q = fmaxf(qa[mf][nf][r], 0.f);
                    float k = fmaxf(ka[mf][nf][r], 0.f);
                    s_part[mf][r] += q * k;
                }
    }
    // reduce s across the 16 column-lanes (stays inside l>>4 groups)
#pragma unroll
    for (int mf = 0; mf < 2; ++mf)
#pragma unroll
        for (int r = 0; r < 4; ++r) {
            float v = s_part[mf][r];
            v += __shfl_xor(v, 1);
            v += __shfl_xor(v, 2);
            v += __shfl_xor(v, 4);
            v += __shfl_xor(v, 8);
            s_part[mf][r] = v;
        }

    // ---- cross-wave reduction over the two wn column-halves (b1 is free) ----
    {
        float* s_red = (float*)b1;   // [2][64]
        if (l15 == 0) {
#pragma unroll
            for (int mf = 0; mf < 2; ++mf)
#pragma unroll
                for (int r = 0; r < 4; ++r)
                    s_red[wn * 64 + m0 + mf * 16 + lk * 4 + r] = s_part[mf][r];
        }
        __syncthreads();
#pragma unroll
        for (int mf = 0; mf < 2; ++mf)
#pragma unroll
            for (int r = 0; r < 4; ++r) {
                int row = m0 + mf * 16 + lk * 4 + r;
                s_part[mf][r] = s_red[row] + s_red[64 + row];
            }
        __syncthreads();
    }

    // ---------------- V phase: A = s * (X Wv) ----------------
    for (int nb = 0; nb < 8; ++nb) {
        const int n0 = nb * 128;
        f32x4 va[2][4] = {};
        for (int k0 = 0; k0 < 16; ++k0) {
            const int kk = k0 * 64;
            __syncthreads();
#pragma unroll
            for (int i = 0; i < 4; ++i) {
                int ch = i * 256 + tid;
                int n  = ch >> 3;
                int s  = ch & 7;
                *(short8*)(b0 + n * 128 + ((s * 16) ^ ((n & 7) << 4))) =
                    *(const short8*)(WvT + (long)(n0 + n) * Cn + kk + s * 8);
            }
            __syncthreads();
#pragma unroll
            for (int ki = 0; ki < 2; ++ki) {
                const int kb  = (kk + ki * 32 + lk * 8) * 2;
                const int r0  = m0 + l15, r1 = m0 + 16 + l15;
                short8 a0 = *(const short8*)(xs + r0 * 2048 + (kb ^ ((r0 & 7) << 4)));
                short8 a1 = *(const short8*)(xs + r1 * 2048 + (kb ^ ((r1 & 7) << 4)));
                const int bkb = (ki * 32 + lk * 8) * 2;
#pragma unroll
                for (int nf = 0; nf < 4; ++nf) {
                    int n = wn * 64 + nf * 16 + l15;
                    short8 bv = *(const short8*)(b0 + n * 128 + (bkb ^ ((n & 7) << 4)));
                    va[0][nf] = __builtin_amdgcn_mfma_f32_16x16x32_bf16(a0, bv, va[0][nf], 0, 0, 0);
                    va[1][nf] = __builtin_amdgcn_mfma_f32_16x16x32_bf16(a1, bv, va[1][nf], 0, 0, 0);
                }
            }
        }
#pragma unroll
        for (int mf = 0; mf < 2; ++mf)
#pragma unroll
            for (int nf = 0; nf < 4; ++nf)
#pragma unroll
                for (int r = 0; r < 4; ++r) {
                    long row = row0 + m0 + mf * 16 + lk * 4 + r;
                    int  col = n0 + wn * 64 + nf * 16 + l15;
                    Aout[row * Cn + col] = s_part[mf][r] * va[mf][nf][r];
                }
    }
}

// ---------------------------------------------------------------------------
// K2: serial recurrence h_t = tanh(W_hh h_{t-1} + b_hh + A_{t-1})
// R6 structure (LDS-staged dot, 3 barriers) + dual-flavor exchange:
//   publish: sc0 store (XCD-L2, serves same-XCD readers fast) + sc1 store
//            (MALL, serves any reader). Same value both paths -> order-free.
//   poll:    alternate 4x sc0 loads (L2 hit, no MALL traffic) with 4x sc1
//            loads (MALL, baseline rate). Tag-in-data self-validates every
//            observation, so correctness holds for ANY WG->XCD placement.
// ---------------------------------------------------------------------------
#define CK(x, bit, vv)                                                        \
    if ((pend & (bit)) && (unsigned)((x) >> 32) == expect) {                  \
        vv = __uint_as_float((unsigned)(x)); pend &= ~(bit);                  \
    }

__global__ __launch_bounds__(256, 2)
void recurrence(const float* __restrict__ A,
                const float* __restrict__ Whh,
                const float* __restrict__ bhh,
                unsigned long long* __restrict__ cbuf,   // [2][8][1024]
                float* __restrict__ out) {
    const int tid = threadIdx.x;
    const int b   = blockIdx.x & 7;
    const int sl  = blockIdx.x >> 3;     // 0..31
    const int j0  = sl * 32;
    const int j   = tid & 31;            // output column within slice
    const int ch  = tid >> 5;            // 0..7, 128-wide input chunk

    __shared__ float sbuf[16000];        // occupancy declaration (62.5 KB)
    float* h_lds = sbuf;                 // [1024]
    float* part  = sbuf + 1024;          // [256]

    // W_hh[j0+j][ch*128 .. +127] register/AGPR-resident, asm-pinned
    float4 w[32];
    const float4* wp = (const float4*)(Whh + (long)(j0 + j) * Cn + ch * 128);
#pragma unroll
    for (int r = 0; r < 32; ++r) w[r] = wp[r];
#pragma unroll
    for (int r = 0; r < 32; ++r) {
        asm volatile("" : "+v"(w[r].x), "+v"(w[r].y), "+v"(w[r].z), "+v"(w[r].w));
    }

    const float bh = (tid < 32) ? bhh[j0 + tid] : 0.f;

    for (int t = 1; t <= Tn; ++t) {
        // prefetch A slice (overlaps the poll)
        float a_val = 0.f;
        if (tid < 32) a_val = A[((long)b * Tn + (t - 1)) * Cn + j0 + tid];

        // ---- dual-flavor poll of my 4 h words ----
        unsigned long long* src =
            cbuf + ((size_t)((t - 1) & 1) * Bn + b) * Cn + tid * 4;
        const unsigned expect = (unsigned)(t - 1);
        float v0 = 0.f, v1 = 0.f, v2 = 0.f, v3 = 0.f;
        unsigned pend = 0xF;
        unsigned long long a0, a1, a2, a3;
        do {
            // L2-scope batch (cheap; detects same-XCD publishes)
            asm volatile(
                "global_load_dwordx2 %0, %4, off sc0\n\t"
                "global_load_dwordx2 %1, %4, off offset:8 sc0\n\t"
                "global_load_dwordx2 %2, %4, off offset:16 sc0\n\t"
                "global_load_dwordx2 %3, %4, off offset:24 sc0\n\t"
                "s_waitcnt vmcnt(0)"
                : "=&v"(a0), "=&v"(a1), "=&v"(a2), "=&v"(a3)
                : "v"(src) : "memory");
            CK(a0, 1u, v0) CK(a1, 2u, v1) CK(a2, 4u, v2) CK(a3, 8u, v3)
            if (!pend) break;
            // MALL-scope batch (correct for any placement)
            asm volatile(
                "global_load_dwordx2 %0, %4, off sc0 sc1\n\t"
                "global_load_dwordx2 %1, %4, off offset:8 sc0 sc1\n\t"
                "global_load_dwordx2 %2, %4, off offset:16 sc0 sc1\n\t"
                "global_load_dwordx2 %3, %4, off offset:24 sc0 sc1\n\t"
                "s_waitcnt vmcnt(0)"
                : "=&v"(a0), "=&v"(a1), "=&v"(a2), "=&v"(a3)
                : "v"(src) : "memory");
            CK(a0, 1u, v0) CK(a1, 2u, v1) CK(a2, 4u, v2) CK(a3, 8u, v3)
        } while (pend);
        *(float4*)(h_lds + tid * 4) = make_float4(v0, v1, v2, v3);
        __syncthreads();

        // partial dot: 128 FMAs against register-resident W, 4 acc chains
        float ax = 0.f, ay = 0.f, az = 0.f, aw = 0.f;
#pragma unroll
        for (int r = 0; r < 32; ++r) {
            float4 h4 = *(const float4*)(h_lds + ch * 128 + r * 4);
            ax = fmaf(w[r].x, h4.x, ax);
            ay = fmaf(w[r].y, h4.y, ay);
            az = fmaf(w[r].z, h4.z, az);
            aw = fmaf(w[r].w, h4.w, aw);
        }
        part[ch * 32 + j] = (ax + ay) + (az + aw);
        __syncthreads();

        if (tid < 32) {
            float s = 0.f;
#pragma unroll
            for (int c = 0; c < 8; ++c) s += part[c * 32 + tid];
            float ht = tanhf(s + a_val + bh);
            // publish FIRST (global critical path): L2 copy + MALL copy
            unsigned long long pk =
                ((unsigned long long)(unsigned)t << 32) | (unsigned long long)__float_as_uint(ht);
            unsigned long long* dst =
                cbuf + ((size_t)(t & 1) * Bn + b) * Cn + j0 + tid;
            asm volatile(
                "global_store_dwordx2 %0, %1, off sc0\n\t"
                "global_store_dwordx2 %0, %1, off sc0 sc1"
                :: "v"(dst), "v"(pk) : "memory");
            out[((long)b * Tn + (t - 1)) * Cn + j0 + tid] = ht;
        }
        __syncthreads();   // protects h_lds/part for next iteration
    }
}

// ---------------------------------------------------------------------------
extern "C" void kernel_launch(void* const* d_in, const int* in_sizes, int n_in,
                              void* d_out, int out_size, void* d_ws, size_t ws_size,
                              hipStream_t stream) {
    const float* X   = (const float*)d_in[0];
    const float* S_n = (const float*)d_in[2];
    const float* W_Q = (const float*)d_in[4];
    const float* W_K = (const float*)d_in[5];
    const float* W_V = (const float*)d_in[6];
    const float* Whh = (const float*)d_in[7];
    const float* bhh = (const float*)d_in[8];
    float* out = (float*)d_out;

    char* ws = (char*)d_ws;
    float*              A     = (float*)ws;                             // 64 MiB
    unsigned short*     WqT   = (unsigned short*)(ws + 67108864);       // 2 MiB
    unsigned short*     WkT   = WqT + 1024 * 1024;
    unsigned short*     WvT   = WkT + 1024 * 1024;
    unsigned long long* cbuf  = (unsigned long long*)(ws + 67108864 + 3 * 2097152); // 128 KiB

    (void)hipFuncSetAttribute((const void*)qkv_fused,
                              hipFuncAttributeMaxDynamicSharedMemorySize, 163840);

    // cbuf zero = (tag 0, value 0.0f) = h_0  -> step 1 is immediately satisfied
    (void)hipMemsetAsync(cbuf, 0, 2 * Bn * Cn * sizeof(unsigned long long), stream);

    transpose_cvt<<<256, 256, 0, stream>>>(W_Q, WqT);
    transpose_cvt<<<256, 256, 0, stream>>>(W_K, WkT);
    transpose_cvt<<<256, 256, 0, stream>>>(W_V, WvT);

    qkv_fused<<<256, 256, 163840, stream>>>(X, WqT, WkT, WvT, A);

    recurrence<<<256, 256, 0, stream>>>(A, Whh, bhh, cbuf, out);

    // S_n passthrough (second output)
    (void)hipMemcpyAsync(out + (long)Bn * Tn * Cn, S_n, Bn * Cn * sizeof(float),
                         hipMemcpyDeviceToDevice, stream);
}